// Round 1
// baseline (74.522 us; speedup 1.0000x reference)
//
#include <hip/hip_runtime.h>

// Binary successive-approximation encoder:
//   v = clip(x, 0, 1); for i in [0,10): s = (v >= 2^-(i+1)); out[b,t,i,c] = s; v -= s*2^-(i+1)
// x: [B=16, T=1024, C=512] f32  ->  out: [B, T, n_bits, C] f32
// Memory-bound: 33.5 MB in + 335.5 MB out. One thread per float4 of input.

#define C_DIM 512

__global__ __launch_bounds__(256) void binenc_kernel(const float* __restrict__ x,
                                                     const int* __restrict__ n_bits_p,
                                                     float* __restrict__ out,
                                                     int n_vec) {
    const int n_bits = *n_bits_p;
    const int vid = blockIdx.x * blockDim.x + threadIdx.x;
    if (vid >= n_vec) return;

    const float4 xin = reinterpret_cast<const float4*>(x)[vid];

    const int fidx = vid << 2;          // flat float index of first lane element
    const int row  = fidx >> 9;         // (b*T + t), since C = 512
    const int c    = fidx & (C_DIM - 1);

    float v[4] = {xin.x, xin.y, xin.z, xin.w};
#pragma unroll
    for (int j = 0; j < 4; ++j) {
        // clip(x, 0, 1) — replicate jnp.clip exactly
        v[j] = fminf(fmaxf(v[j], 0.0f), 1.0f);
    }

    float* outbase = out + row * n_bits * C_DIM + c;
    float decision = 0.5f;
    for (int i = 0; i < n_bits; ++i) {
        float4 s;
        float sv[4];
#pragma unroll
        for (int j = 0; j < 4; ++j) {
            sv[j] = (v[j] >= decision) ? 1.0f : 0.0f;
            v[j]  = v[j] - sv[j] * decision;   // exact (power-of-two subtraction)
        }
        s.x = sv[0]; s.y = sv[1]; s.z = sv[2]; s.w = sv[3];
        *reinterpret_cast<float4*>(outbase + i * C_DIM) = s;
        decision *= 0.5f;
    }
}

extern "C" void kernel_launch(void* const* d_in, const int* in_sizes, int n_in,
                              void* d_out, int out_size, void* d_ws, size_t ws_size,
                              hipStream_t stream) {
    const float* x        = (const float*)d_in[0];
    const int*   n_bits_p = (const int*)d_in[1];
    float*       out      = (float*)d_out;

    const int n_elems = in_sizes[0];        // 16*1024*512 = 8,388,608
    const int n_vec   = n_elems >> 2;       // float4 granularity (C=512 divisible by 4)
    const int block   = 256;
    const int grid    = (n_vec + block - 1) / block;

    binenc_kernel<<<grid, block, 0, stream>>>(x, n_bits_p, out, n_vec);
}